// Round 7
// baseline (66.107 us; speedup 1.0000x reference)
//
#include <hip/hip_runtime.h>
#include <stdint.h>

#define T_DIM 4096
#define S_DIM 16384          // 4 batches x 4096
#define EPSF 1e-12f

typedef __attribute__((ext_vector_type(8))) short   short8v;
typedef __attribute__((ext_vector_type(4))) float   float4v;
typedef __attribute__((ext_vector_type(2))) float   float2v;
typedef __attribute__((ext_vector_type(4))) uint32_t uint4v;

__device__ __forceinline__ unsigned short f2bf_rne(float f) {
    uint32_t u = __builtin_bit_cast(uint32_t, f);
    return (unsigned short)((u + 0x7fffu + ((u >> 16) & 1u)) >> 16);
}
__device__ __forceinline__ uint32_t cvtpk(float lo, float hi) {
    uint32_t r;
    asm("v_cvt_pk_bf16_f32 %0, %1, %2" : "=v"(r) : "v"(lo), "v"(hi));
    return r;
}

// ---------------------------------------------------------------------------
// K0: conv_w [k=4096][n=64] f32 -> bf16 fragment stream wfrag[cc][nt][h][ln]x16B
//     granule (cc,nt,h,ln) holds W[cc*64 + h*32 + (ln>>4)*8 + j][nt*16+(ln&15)]
// ---------------------------------------------------------------------------
__global__ __launch_bounds__(256) void k_convert(const float* __restrict__ conv_w,
                                                 unsigned short* __restrict__ wfrag) {
    __shared__ unsigned short lb[64][65];
    int tid = threadIdx.x;
    int cc  = blockIdx.x;                       // 0..63
    for (int i = tid; i < 4096; i += 256) {     // coalesced read of 16KB slab
        lb[i >> 6][i & 63] = f2bf_rne(conv_w[((size_t)cc << 12) + i]);
    }
    __syncthreads();
    for (int gi = tid; gi < 512; gi += 256) {
        int nt = gi >> 7, h = (gi >> 6) & 1, ln = gi & 63;
        int n  = (nt << 4) + (ln & 15);
        int kb = (h << 5) + ((ln >> 4) << 3);
        uint4v u;
        #pragma unroll
        for (int q = 0; q < 4; ++q)
            u[q] = (uint32_t)lb[kb + 2 * q][n] | ((uint32_t)lb[kb + 2 * q + 1][n] << 16);
        *(uint4v*)(wfrag + ((size_t)cc << 12) + (gi << 3)) = u;
    }
}

// ---------------------------------------------------------------------------
// K1: dots + norm partials.  Block = 64 positions (lane = position).
// ---------------------------------------------------------------------------
__global__ __launch_bounds__(256) void k_dotsP(const float* __restrict__ x,
                                               const float* __restrict__ w,
                                               float* __restrict__ P) {
    __shared__ float xt[78 * 65];       // pitch 65, rows s0..s0+77
    __shared__ float pd[4][64][17];
    __shared__ float dsq[64][17];
    int tid = threadIdx.x, lane = tid & 63, wv = tid >> 6;
    int s0 = blockIdx.x << 6;
    int bt0 = s0 & (T_DIM - 1);
    for (int i = tid; i < 78 * 16; i += 256) {
        int r = i >> 4, c4 = (i & 15) << 2;
        float4v v = {0.f, 0.f, 0.f, 0.f};
        if (bt0 + r < T_DIM) v = *(const float4v*)(x + (((size_t)(s0 + r)) << 6) + c4);
        #pragma unroll
        for (int q = 0; q < 4; ++q) xt[r * 65 + c4 + q] = v[q];
    }
    __syncthreads();
    float acc[15];
    #pragma unroll
    for (int j = 0; j < 15; ++j) acc[j] = 0.f;
    int c0 = wv << 4;
    for (int c = c0; c < c0 + 16; ++c) {
        const float* base = &xt[lane * 65 + c];
        float xl = base[0];
        #pragma unroll
        for (int j = 0; j < 15; ++j) acc[j] += xl * base[j * 65];
    }
    #pragma unroll
    for (int j = 0; j < 15; ++j) pd[wv][lane][j] = acc[j];
    __syncthreads();
    for (int i = tid; i < 960; i += 256) {      // i = j*64 + s
        int s = i & 63, j = i >> 6;
        float d = pd[0][s][j] + pd[1][s][j] + pd[2][s][j] + pd[3][s][j];
        dsq[s][j] = d * d;
    }
    __syncthreads();
    for (int i = tid; i < 960; i += 256) {      // i = l*64 + s  (coalesced P writes)
        int s = i & 63, l = i >> 6;
        float sum = w[l] * dsq[s][0];
        for (int j = 1; j <= 14 - l; ++j) sum += 2.f * w[l + j] * dsq[s][j];
        P[(size_t)l * S_DIM + s0 + s] = sum;
    }
}

// ---------------------------------------------------------------------------
// K2: rsq[s] = rsqrt(max(sum_l w_l * P[l][s+l-7], eps))
// ---------------------------------------------------------------------------
__global__ __launch_bounds__(256) void k_rsq(const float* __restrict__ P,
                                             const float* __restrict__ w,
                                             float* __restrict__ rsq) {
    int s = blockIdx.x * 256 + threadIdx.x;
    int t = s & (T_DIM - 1);
    float sum = 0.f;
    #pragma unroll
    for (int l = 0; l < 15; ++l) {
        int tp = t + l - 7;
        if (0 <= tp && tp < T_DIM) sum += w[l] * P[(size_t)l * S_DIM + s + l - 7];
    }
    rsq[s] = rsqrtf(fmaxf(sum, EPSF));
}

// ---------------------------------------------------------------------------
// K3: GEMM g_part[split][s][n] (M=16384, K=4096, N=64), F on the fly.
// nt-SPECIALIZED scaled-h form: wave wv owns n-quadrant nt=wv, all 64 rows.
// Was L1-BW-bound: all 4 waves loaded IDENTICAL 8 granules/iter (2MB/CU).
// Now: 2 granules/iter, zero cross-wave redundancy (512KB/CU).
//   h[m][n]   = sum_d bf16(x[m,d]) * W[c*64+d][n]   (2 chained MFMAs, C=0)
//   acc[m][n]+= x[m,c] * h[m][n]                    (f32 FMA, x_c exact)
// xd fragments fixed across the whole K-loop. unroll 1 (full unroll
// miscompiles, R5 bisection). 4-way K-split: 1024 blocks, 4/CU.
// ---------------------------------------------------------------------------
__global__ __launch_bounds__(256) void k_gemm(const float* __restrict__ x,
                                              const unsigned short* __restrict__ wfrag,
                                              float* __restrict__ g) {
    int tid = threadIdx.x, lane = tid & 63, wv = tid >> 6;   // wv = n-quadrant
    int split = blockIdx.x & 3;
    int m0 = (blockIdx.x >> 2) << 6;
    int c0 = split << 4;

    int arow_l = lane & 15;
    int kgrp   = (lane >> 4) << 3;
    int srow_b = (lane >> 4) << 2;     // C/D row base within a 16-tile

    // fixed A-operands: xd[rg][h] = bf16(x[m0+rg*16+(lane&15)][h*32+kgrp+j])
    short8v xd[4][2];
    #pragma unroll
    for (int rg = 0; rg < 4; ++rg) {
        const float* xr = x + (((size_t)(m0 + rg * 16 + arow_l)) << 6);
        #pragma unroll
        for (int h = 0; h < 2; ++h) {
            float4v v0 = *(const float4v*)(xr + h * 32 + kgrp);
            float4v v1 = *(const float4v*)(xr + h * 32 + kgrp + 4);
            union { uint32_t u[4]; short8v s; } a;
            a.u[0] = cvtpk(v0[0], v0[1]); a.u[1] = cvtpk(v0[2], v0[3]);
            a.u[2] = cvtpk(v1[0], v1[1]); a.u[3] = cvtpk(v1[2], v1[3]);
            xd[rg][h] = a.s;
        }
    }

    float4v acc[4];
    #pragma unroll
    for (int rg = 0; rg < 4; ++rg)
        #pragma unroll
        for (int j = 0; j < 4; ++j) acc[rg][j] = 0.f;

    const short8v* wfb = (const short8v*)wfrag + ((size_t)wv << 7) + lane;

    #pragma unroll 1
    for (int cg = 0; cg < 8; ++cg) {            // 2 c-columns per group
        int cbase = c0 + (cg << 1);
        // x-scales: xs[rg][j] = x[m0+rg*16+srow_b+j][cbase..cbase+1]
        float2v xs[4][4];
        #pragma unroll
        for (int rg = 0; rg < 4; ++rg)
            #pragma unroll
            for (int j = 0; j < 4; ++j)
                xs[rg][j] = *(const float2v*)(
                    x + (((size_t)(m0 + rg * 16 + srow_b + j)) << 6) + cbase);
        #pragma unroll
        for (int cc = 0; cc < 2; ++cc) {
            const short8v* bp = wfb + (((size_t)(cbase + cc)) << 9);
            short8v b0 = bp[0];                 // h=0 granule
            short8v b1 = bp[64];                // h=1 granule
            #pragma unroll
            for (int rg = 0; rg < 4; ++rg) {
                float4v hh = {0.f, 0.f, 0.f, 0.f};
                hh = __builtin_amdgcn_mfma_f32_16x16x32_bf16(xd[rg][0], b0, hh, 0, 0, 0);
                hh = __builtin_amdgcn_mfma_f32_16x16x32_bf16(xd[rg][1], b1, hh, 0, 0, 0);
                #pragma unroll
                for (int j = 0; j < 4; ++j)
                    acc[rg][j] += xs[rg][j][cc] * hh[j];
            }
        }
    }

    // epilogue: row = m0+rg*16+srow_b+j, col = wv*16 + (lane&15)
    float* gp = g + (size_t)split * ((size_t)S_DIM * 64);
    int col = (wv << 4) + arow_l;
    #pragma unroll
    for (int rg = 0; rg < 4; ++rg)
        #pragma unroll
        for (int j = 0; j < 4; ++j)
            gp[((size_t)(m0 + rg * 16 + srow_b + j) << 6) + col] = acc[rg][j];
}

// ---------------------------------------------------------------------------
// K4: out[s,n] = (sum_l w_l * G[s+l-7, n]) * rsq[s] + b[n],  G = sum of 4 partials
// ---------------------------------------------------------------------------
__global__ __launch_bounds__(256) void k_final(const float* __restrict__ g,
                                               const float* __restrict__ rsq,
                                               const float* __restrict__ w,
                                               const float* __restrict__ conv_b,
                                               float* __restrict__ out) {
    int lane = threadIdx.x & 63, wv = threadIdx.x >> 6;
    int wid = blockIdx.x * 4 + wv;           // 0..1023
    int t0 = wid << 4;
    int bt0 = t0 & (T_DIM - 1);
    const size_t SP = (size_t)S_DIM * 64;
    float r[30];
    #pragma unroll
    for (int i = 0; i < 30; ++i) {
        int tr = bt0 - 7 + i;
        r[i] = 0.f;
        if (0 <= tr && tr < T_DIM) {
            const float* p = g + (((size_t)(t0 - 7 + i)) << 6) + lane;
            r[i] = (p[0] + p[SP]) + (p[2 * SP] + p[3 * SP]);
        }
    }
    float bn = conv_b[lane];
    #pragma unroll
    for (int i = 0; i < 16; ++i) {
        float acc = 0.f;
        #pragma unroll
        for (int l = 0; l < 15; ++l) acc += w[l] * r[i + l];
        out[(((size_t)(t0 + i)) << 6) + lane] = acc * rsq[t0 + i] + bn;
    }
}

// ---------------------------------------------------------------------------
extern "C" void kernel_launch(void* const* d_in, const int* in_sizes, int n_in,
                              void* d_out, int out_size, void* d_ws, size_t ws_size,
                              hipStream_t stream) {
    const float* x      = (const float*)d_in[0];
    const float* w      = (const float*)d_in[1];
    const float* conv_w = (const float*)d_in[2];
    const float* conv_b = (const float*)d_in[3];
    float* out = (float*)d_out;

    char* ws = (char*)d_ws;
    unsigned short* wfrag = (unsigned short*)ws;                     //    524,288 B
    float* g              = (float*)(ws + 524288);                   // 16,777,216 B (4 K-split partials)
    float* P              = (float*)(ws + 524288 + 16777216);        //  1,048,576 B
    float* rsq            = P + (size_t)15 * S_DIM;

    hipLaunchKernelGGL(k_convert, dim3(64),   dim3(256), 0, stream, conv_w, wfrag);
    hipLaunchKernelGGL(k_dotsP,   dim3(256),  dim3(256), 0, stream, x, w, P);
    hipLaunchKernelGGL(k_gemm,    dim3(1024), dim3(256), 0, stream, x, wfrag, g);
    hipLaunchKernelGGL(k_rsq,     dim3(64),   dim3(256), 0, stream, P, w, rsq);
    hipLaunchKernelGGL(k_final,   dim3(256),  dim3(256), 0, stream, g, rsq, w, conv_b, out);
}

// Round 8
// 51.949 us; speedup vs baseline: 1.2725x; 1.2725x over previous
//
#include <hip/hip_runtime.h>
#include <stdint.h>

#define T_DIM 4096
#define S_DIM 16384          // 4 batches x 4096
#define EPSF 1e-12f

typedef __attribute__((ext_vector_type(8))) short   short8v;
typedef __attribute__((ext_vector_type(4))) float   float4v;
typedef __attribute__((ext_vector_type(4))) uint32_t uint4v;

__device__ __forceinline__ unsigned short f2bf_rne(float f) {
    uint32_t u = __builtin_bit_cast(uint32_t, f);
    return (unsigned short)((u + 0x7fffu + ((u >> 16) & 1u)) >> 16);
}
__device__ __forceinline__ uint32_t cvtpk(float lo, float hi) {
    uint32_t r;
    asm("v_cvt_pk_bf16_f32 %0, %1, %2" : "=v"(r) : "v"(lo), "v"(hi));
    return r;
}

#define GLOAD_LDS16(gsrc, ldst)                                                     \
    __builtin_amdgcn_global_load_lds(                                               \
        (const __attribute__((address_space(1))) void*)(gsrc),                      \
        (__attribute__((address_space(3))) void*)(ldst), 16, 0, 0)

// ---------------------------------------------------------------------------
// K0: conv_w [k=4096][n=64] f32 -> bf16 fragment stream wfrag[cc][nt][h][ln]x16B
//     granule (cc,nt,h,ln) holds W[cc*64 + h*32 + (ln>>4)*8 + j][nt*16+(ln&15)]
// ---------------------------------------------------------------------------
__global__ __launch_bounds__(256) void k_convert(const float* __restrict__ conv_w,
                                                 unsigned short* __restrict__ wfrag) {
    __shared__ unsigned short lb[64][65];
    int tid = threadIdx.x;
    int cc  = blockIdx.x;                       // 0..63
    for (int i = tid; i < 4096; i += 256) {     // coalesced read of 16KB slab
        lb[i >> 6][i & 63] = f2bf_rne(conv_w[((size_t)cc << 12) + i]);
    }
    __syncthreads();
    for (int gi = tid; gi < 512; gi += 256) {
        int nt = gi >> 7, h = (gi >> 6) & 1, ln = gi & 63;
        int n  = (nt << 4) + (ln & 15);
        int kb = (h << 5) + ((ln >> 4) << 3);
        uint4v u;
        #pragma unroll
        for (int q = 0; q < 4; ++q)
            u[q] = (uint32_t)lb[kb + 2 * q][n] | ((uint32_t)lb[kb + 2 * q + 1][n] << 16);
        *(uint4v*)(wfrag + ((size_t)cc << 12) + (gi << 3)) = u;
    }
}

// ---------------------------------------------------------------------------
// K1: dots + norm partials.  Block = 64 positions (lane = position).
// ---------------------------------------------------------------------------
__global__ __launch_bounds__(256) void k_dotsP(const float* __restrict__ x,
                                               const float* __restrict__ w,
                                               float* __restrict__ P) {
    __shared__ float xt[78 * 65];       // pitch 65, rows s0..s0+77
    __shared__ float pd[4][64][17];
    __shared__ float dsq[64][17];
    int tid = threadIdx.x, lane = tid & 63, wv = tid >> 6;
    int s0 = blockIdx.x << 6;
    int bt0 = s0 & (T_DIM - 1);
    for (int i = tid; i < 78 * 16; i += 256) {
        int r = i >> 4, c4 = (i & 15) << 2;
        float4v v = {0.f, 0.f, 0.f, 0.f};
        if (bt0 + r < T_DIM) v = *(const float4v*)(x + (((size_t)(s0 + r)) << 6) + c4);
        #pragma unroll
        for (int q = 0; q < 4; ++q) xt[r * 65 + c4 + q] = v[q];
    }
    __syncthreads();
    float acc[15];
    #pragma unroll
    for (int j = 0; j < 15; ++j) acc[j] = 0.f;
    int c0 = wv << 4;
    for (int c = c0; c < c0 + 16; ++c) {
        const float* base = &xt[lane * 65 + c];
        float xl = base[0];
        #pragma unroll
        for (int j = 0; j < 15; ++j) acc[j] += xl * base[j * 65];
    }
    #pragma unroll
    for (int j = 0; j < 15; ++j) pd[wv][lane][j] = acc[j];
    __syncthreads();
    for (int i = tid; i < 960; i += 256) {      // i = j*64 + s
        int s = i & 63, j = i >> 6;
        float d = pd[0][s][j] + pd[1][s][j] + pd[2][s][j] + pd[3][s][j];
        dsq[s][j] = d * d;
    }
    __syncthreads();
    for (int i = tid; i < 960; i += 256) {      // i = l*64 + s  (coalesced P writes)
        int s = i & 63, l = i >> 6;
        float sum = w[l] * dsq[s][0];
        for (int j = 1; j <= 14 - l; ++j) sum += 2.f * w[l + j] * dsq[s][j];
        P[(size_t)l * S_DIM + s0 + s] = sum;
    }
}

// ---------------------------------------------------------------------------
// K2: rsq[s] = rsqrt(max(sum_l w_l * P[l][s+l-7], eps))
// ---------------------------------------------------------------------------
__global__ __launch_bounds__(256) void k_rsq(const float* __restrict__ P,
                                             const float* __restrict__ w,
                                             float* __restrict__ rsq) {
    int s = blockIdx.x * 256 + threadIdx.x;
    int t = s & (T_DIM - 1);
    float sum = 0.f;
    #pragma unroll
    for (int l = 0; l < 15; ++l) {
        int tp = t + l - 7;
        if (0 <= tp && tp < T_DIM) sum += w[l] * P[(size_t)l * S_DIM + s + l - 7];
    }
    rsq[s] = rsqrtf(fmaxf(sum, EPSF));
}

// ---------------------------------------------------------------------------
// K3: GEMM g_part[split][s][n] (M=16384, K=4096, N=64), F on the fly.
// R6 was L1-BW-bound: every wave loaded all 8 granules/iter (2 MB/CU total).
// Fix: stage the 8KB chunk ONCE per block into LDS (512 KB/CU), T3-minimal
// 2-phase schedule (stage next chunk issued BEFORE compute; one full-drain
// __syncthreads per iter — no counted-vmcnt races). ds_read_b128 lane-linear
// on the granule stream = conflict-free. unroll 2 only (full unroll
// miscompiles, R5). A-gen/MFMA/epilogue identical to R6 (absmax must stay
// exactly 4.882812e-4).
// ---------------------------------------------------------------------------
__global__ __launch_bounds__(256) void k_gemm(const float* __restrict__ x,
                                              const unsigned short* __restrict__ wfrag,
                                              float* __restrict__ g) {
    __shared__ alignas(16) unsigned short wbuf[2][4096];   // 2 x 8KB chunk
    int tid = threadIdx.x, lane = tid & 63, wv = tid >> 6;
    int split = blockIdx.x & 3;
    int m0 = (blockIdx.x >> 2) << 6;
    int c0 = split << 4;

    int prow = (wv << 4) + (lane & 15);
    int kgrp = (lane >> 4) << 3;
    const float* xr = x + (((size_t)(m0 + prow)) << 6);
    // A-operand d-half registers (fixed across the K loop)
    float4v p00 = *(const float4v*)(xr + kgrp);
    float4v p01 = *(const float4v*)(xr + kgrp + 4);
    float4v p10 = *(const float4v*)(xr + 32 + kgrp);
    float4v p11 = *(const float4v*)(xr + 36 + kgrp);

    const char* wsb = (const char*)wfrag;
    // stage = 8KB chunk: 2 rounds of 256 lanes x 16B; LDS dest wave-uniform
#define STAGE_CHUNK(bi, c) do {                                                   \
        GLOAD_LDS16(wsb + ((size_t)(c) << 13) + (tid << 4),                       \
                    (char*)&wbuf[bi][0] + (wv << 10));                            \
        GLOAD_LDS16(wsb + ((size_t)(c) << 13) + 4096 + (tid << 4),                \
                    (char*)&wbuf[bi][0] + 4096 + (wv << 10));                     \
    } while (0)

    float4v acc[4];
    #pragma unroll
    for (int nt = 0; nt < 4; ++nt)
        #pragma unroll
        for (int j = 0; j < 4; ++j) acc[nt][j] = 0.f;

    const short8v* fb0 = (const short8v*)&wbuf[0][0];
    const short8v* fb1 = (const short8v*)&wbuf[1][0];

    STAGE_CHUNK(0, c0);
    __syncthreads();                    // chunk 0 resident

    #pragma unroll 2
    for (int ci = 0; ci < 16; ++ci) {
        if (ci < 15) STAGE_CHUNK((ci + 1) & 1, c0 + ci + 1);   // overlaps compute

        const short8v* fb = (ci & 1) ? fb1 : fb0;
        short8v b0 = fb[lane];
        short8v b1 = fb[64 + lane];
        short8v b2 = fb[128 + lane];
        short8v b3 = fb[192 + lane];
        short8v b4 = fb[256 + lane];
        short8v b5 = fb[320 + lane];
        short8v b6 = fb[384 + lane];
        short8v b7 = fb[448 + lane];

        float xc = xr[c0 + ci];         // scalar L1-hit load
        union { uint32_t u[4]; short8v s; } a0, a1;
        float4v q0 = p00 * xc, q1 = p01 * xc, q2 = p10 * xc, q3 = p11 * xc;
        a0.u[0] = cvtpk(q0[0], q0[1]); a0.u[1] = cvtpk(q0[2], q0[3]);
        a0.u[2] = cvtpk(q1[0], q1[1]); a0.u[3] = cvtpk(q1[2], q1[3]);
        a1.u[0] = cvtpk(q2[0], q2[1]); a1.u[1] = cvtpk(q2[2], q2[3]);
        a1.u[2] = cvtpk(q3[0], q3[1]); a1.u[3] = cvtpk(q3[2], q3[3]);

        acc[0] = __builtin_amdgcn_mfma_f32_16x16x32_bf16(a0.s, b0, acc[0], 0, 0, 0);
        acc[0] = __builtin_amdgcn_mfma_f32_16x16x32_bf16(a1.s, b1, acc[0], 0, 0, 0);
        acc[1] = __builtin_amdgcn_mfma_f32_16x16x32_bf16(a0.s, b2, acc[1], 0, 0, 0);
        acc[1] = __builtin_amdgcn_mfma_f32_16x16x32_bf16(a1.s, b3, acc[1], 0, 0, 0);
        acc[2] = __builtin_amdgcn_mfma_f32_16x16x32_bf16(a0.s, b4, acc[2], 0, 0, 0);
        acc[2] = __builtin_amdgcn_mfma_f32_16x16x32_bf16(a1.s, b5, acc[2], 0, 0, 0);
        acc[3] = __builtin_amdgcn_mfma_f32_16x16x32_bf16(a0.s, b6, acc[3], 0, 0, 0);
        acc[3] = __builtin_amdgcn_mfma_f32_16x16x32_bf16(a1.s, b7, acc[3], 0, 0, 0);

        __syncthreads();                // full drain: next chunk resident, reads done
    }
#undef STAGE_CHUNK

    // epilogue: C/D layout col = lane&15 (n), row = (lane>>4)*4 + j
    float* gp = g + (size_t)split * ((size_t)S_DIM * 64);
    int crow0 = m0 + (wv << 4) + ((lane >> 4) << 2);
    int col0 = lane & 15;
    #pragma unroll
    for (int nt = 0; nt < 4; ++nt)
        #pragma unroll
        for (int j = 0; j < 4; ++j)
            gp[((size_t)(crow0 + j) << 6) + (nt << 4) + col0] = acc[nt][j];
}

// ---------------------------------------------------------------------------
// K4: out[s,n] = (sum_l w_l * G[s+l-7, n]) * rsq[s] + b[n],  G = sum of 4 partials
// ---------------------------------------------------------------------------
__global__ __launch_bounds__(256) void k_final(const float* __restrict__ g,
                                               const float* __restrict__ rsq,
                                               const float* __restrict__ w,
                                               const float* __restrict__ conv_b,
                                               float* __restrict__ out) {
    int lane = threadIdx.x & 63, wv = threadIdx.x >> 6;
    int wid = blockIdx.x * 4 + wv;           // 0..1023
    int t0 = wid << 4;
    int bt0 = t0 & (T_DIM - 1);
    const size_t SP = (size_t)S_DIM * 64;
    float r[30];
    #pragma unroll
    for (int i = 0; i < 30; ++i) {
        int tr = bt0 - 7 + i;
        r[i] = 0.f;
        if (0 <= tr && tr < T_DIM) {
            const float* p = g + (((size_t)(t0 - 7 + i)) << 6) + lane;
            r[i] = (p[0] + p[SP]) + (p[2 * SP] + p[3 * SP]);
        }
    }
    float bn = conv_b[lane];
    #pragma unroll
    for (int i = 0; i < 16; ++i) {
        float acc = 0.f;
        #pragma unroll
        for (int l = 0; l < 15; ++l) acc += w[l] * r[i + l];
        out[(((size_t)(t0 + i)) << 6) + lane] = acc * rsq[t0 + i] + bn;
    }
}

// ---------------------------------------------------------------------------
extern "C" void kernel_launch(void* const* d_in, const int* in_sizes, int n_in,
                              void* d_out, int out_size, void* d_ws, size_t ws_size,
                              hipStream_t stream) {
    const float* x      = (const float*)d_in[0];
    const float* w      = (const float*)d_in[1];
    const float* conv_w = (const float*)d_in[2];
    const float* conv_b = (const float*)d_in[3];
    float* out = (float*)d_out;

    char* ws = (char*)d_ws;
    unsigned short* wfrag = (unsigned short*)ws;                     //    524,288 B
    float* g              = (float*)(ws + 524288);                   // 16,777,216 B (4 K-split partials)
    float* P              = (float*)(ws + 524288 + 16777216);        //  1,048,576 B
    float* rsq            = P + (size_t)15 * S_DIM;

    hipLaunchKernelGGL(k_convert, dim3(64),   dim3(256), 0, stream, conv_w, wfrag);
    hipLaunchKernelGGL(k_dotsP,   dim3(256),  dim3(256), 0, stream, x, w, P);
    hipLaunchKernelGGL(k_gemm,    dim3(1024), dim3(256), 0, stream, x, wfrag, g);
    hipLaunchKernelGGL(k_rsq,     dim3(64),   dim3(256), 0, stream, P, w, rsq);
    hipLaunchKernelGGL(k_final,   dim3(256),  dim3(256), 0, stream, g, rsq, w, conv_b, out);
}